// Round 7
// baseline (8784.229 us; speedup 1.0000x reference)
//
#include <hip/hip_runtime.h>
#include <hip/hip_fp16.h>
#include <stdint.h>
#include <stddef.h>

// DRNN (dilated 3-layer LSTM), B=128, T=1024, F=128, H=256, dil=[1,2,4].
//  - Input GEMMs hoisted out of recurrence (f16 MFMA 16x16x32), G in 67MB chunks.
//  - R10: R3..R9 all pinned at ~2.1-2.6us/step across SIX different compute
//    structures. The invariant: cross-WG h-exchange via agent-scope atomics.
//    gfx950 XCD L2s are non-coherent -> agent scope is serviced at the DEVICE
//    coherent point (L3): publish ~700cy + poll retry ~700cy + quantization
//    ~= the 2us floor. Placement can't fix scope. Fix: ZERO exchange.
//      * grid 16 x 512: WG g owns batches [8g,8g+8) with ALL 256 h-dims.
//        Full W_hh per WG: 200 VGPR/lane (50 B-frags: kt 0-5 all ct + ct0
//        kt6,7) + 112KB LDS (14 frags: ct 1-7, kt 6-7). NOT pinned (R6
//        lesson): allocator may remat overflow from L2, graceful.
//      * h lives in LDS hbuf[2 parity][8][256] f16, 16B-chunk XOR swizzle
//        (chunk ^ row<<2: A-frag ds_read_b128 at the 4-cycle floor).
//      * 2 intra-CU barriers/step (lgkm-only: G prefetch stays in flight).
//        No atomics, no tags, no spin. Wave w: gate w>>1, dim-half w&1.
//      * Cell: wave = batch, lane = 4 dims; gq[4][8][264] f32 via LDS
//        (D-mapping verbatim from verified R7); G prefetched depth-1 (8 reg).
//    Step model: LDS ~244KB/step ~950cy (floor), MFMA 620cy overlapped,
//    cell ~400cy -> ~0.5us/step vs 2.27 before.

typedef _Float16 f16;
typedef _Float16 v2h __attribute__((ext_vector_type(2)));
typedef _Float16 v8h __attribute__((ext_vector_type(8)));
typedef __fp16 h2_raw __attribute__((ext_vector_type(2)));
typedef __fp16 h8_raw __attribute__((ext_vector_type(8)));
typedef float v4f __attribute__((ext_vector_type(4)));
typedef unsigned long long u64;

#define DEVINL static __device__ __forceinline__

DEVINL float sigm(float x) { return 1.0f / (1.0f + __expf(-x)); }
DEVINL float tanh_(float x) {
  x = fminf(fmaxf(x, -15.0f), 15.0f);
  float e = __expf(-2.0f * x);
  return (1.0f - e) / (1.0f + e);
}
DEVINL uint32_t pk2(float a, float b) {
  return __builtin_bit_cast(uint32_t, __builtin_amdgcn_cvt_pkrtz(a, b));
}
DEVINL v4f mfma_16x16x32(v8h a, v8h b, v4f c) {
  return __builtin_amdgcn_mfma_f32_16x16x32_f16(__builtin_bit_cast(h8_raw, a),
                                                __builtin_bit_cast(h8_raw, b), c,
                                                0, 0, 0);
}

// Workgroup barrier WITHOUT vmcnt drain: LDS ordered (lgkmcnt(0)), global
// loads/stores stay in flight (compiler inserts counted vmcnt at use).
DEVINL void wg_barrier() {
  __builtin_amdgcn_sched_barrier(0);
  asm volatile("s_waitcnt lgkmcnt(0)" ::: "memory");
  __builtin_amdgcn_s_barrier();
  asm volatile("" ::: "memory");
  __builtin_amdgcn_sched_barrier(0);
}

// hbuf [2][8][256] f16; logical (row, 16B-chunk c 0..31) -> stored chunk c^(row<<2)
DEVINL int hb_off(int par, int row, int c) {
  return par * 4096 + row * 512 + ((c ^ (row << 2)) << 4);
}

// ---------------- prep ----------------

__global__ void k_cvt_x(const float2* __restrict__ src, uint32_t* __restrict__ dst, int n2) {
  int i = blockIdx.x * blockDim.x + threadIdx.x;
  int st = gridDim.x * blockDim.x;
  for (; i < n2; i += st) {
    float2 v = src[i];
    dst[i] = pk2(v.x, v.y);
  }
}

__global__ void k_prep_w(const float* __restrict__ wih0, const float* __restrict__ whh0,
                         const float* __restrict__ wih1, const float* __restrict__ whh1,
                         const float* __restrict__ wih2, const float* __restrict__ whh2,
                         const float* __restrict__ bi0, const float* __restrict__ bh0,
                         const float* __restrict__ bi1, const float* __restrict__ bh1,
                         const float* __restrict__ bi2, const float* __restrict__ bh2,
                         f16* wih0f, f16* whh0f, f16* wih1f, f16* whh1f,
                         f16* wih2f, f16* whh2f,
                         float* bias0, float* bias1, float* bias2) {
  int i = blockIdx.x * blockDim.x + threadIdx.x;  // grid covers 262144
  if (i < 131072) wih0f[i] = (f16)wih0[i];
  whh0f[i] = (f16)whh0[i];
  wih1f[i] = (f16)wih1[i];
  whh1f[i] = (f16)whh1[i];
  wih2f[i] = (f16)wih2[i];
  whh2f[i] = (f16)whh2[i];
  if (i < 1024) {
    bias0[i] = bi0[i] + bh0[i];
    bias1[i] = bi1[i] + bh1[i];
    bias2[i] = bi2[i] + bh2[i];
  }
}

// ---------------- input GEMM (unchanged) ----------------

template <int K>
__launch_bounds__(256)
__global__ void k_gemm(const f16* __restrict__ A, int Tb, int t0,
                       const f16* __restrict__ W, const float* __restrict__ bias,
                       f16* __restrict__ G) {
  constexpr int LDK = K + 8;
  __shared__ f16 As[64 * LDK];
  int b = blockIdx.x >> 2, tb = blockIdx.x & 3;
  const f16* Ablk = A + ((size_t)b * Tb + t0 + tb * 64) * K;
  int tid = threadIdx.x;

  constexpr int NV = 64 * K / 8;
  const uint4* src = (const uint4*)Ablk;
  for (int i = tid; i < NV; i += 256) {
    int e = i * 8;
    int r = e / K, c0 = e % K;
    *(uint4*)&As[r * LDK + c0] = src[i];
  }
  __syncthreads();

  int wave = tid >> 6, lane = tid & 63;
  int lm = lane & 15, lk = (lane >> 4) * 8;

  v8h af[K / 32];
#pragma unroll
  for (int kc = 0; kc < K / 32; ++kc)
    af[kc] = *(const v8h*)&As[(wave * 16 + lm) * LDK + kc * 32 + lk];

  size_t grow0 = (size_t)b * 256 + tb * 64 + wave * 16;
  for (int nt = 0; nt < 64; ++nt) {
    v4f acc = {0.0f, 0.0f, 0.0f, 0.0f};
    const f16* Wrow = W + (size_t)(nt * 16 + lm) * K + lk;
#pragma unroll
    for (int kc = 0; kc < K / 32; ++kc) {
      v8h bf = *(const v8h*)(Wrow + kc * 32);
      acc = mfma_16x16x32(af[kc], bf, acc);
    }
    float bv = bias[nt * 16 + lm];
#pragma unroll
    for (int r = 0; r < 4; ++r) {
      int m = (lane >> 4) * 4 + r;
      G[(grow0 + m) * 1024 + nt * 16 + lm] = (f16)(acc[r] + bv);
    }
  }
}

// ---------------- recurrence (R10: single-WG batch-group, zero exchange) ----
// grid 16 x 512. WG g: batches [8g, 8g+8), all 256 dims, full W_hh.
// Wave w: gate q=w>>1, dim-half dh=w&1 -> cols q*256+dh*128+ct*16+arow,
// ct 0..7, K=256 = 8 kt. B-frag (ct,kt): kt<6 or (ct==0) in VGPR; rest LDS.
// Per step: [2 ct-passes: 8 A-reads + 32 MFMA + gq writes] BAR1
//           [cell (wave=batch, lane=4 dims), hbuf[p^1] write, outputs,
//            G prefetch s+1] BAR2.

template <int LAYER>
__launch_bounds__(512, 1)
__global__ void k_rec(const f16* __restrict__ G,   // chunk [128][256][1024] f16
                      const f16* __restrict__ Whh, // [1024][256] f16
                      int t0, int steps,           // steps == 256
                      f16* __restrict__ Hout, float* __restrict__ y,
                      float* __restrict__ hstate, float* __restrict__ cstate) {
  int g = blockIdx.x;                    // 0..15
  int tid = threadIdx.x;
  int lane = tid & 63, w = tid >> 6;
  int q = w >> 1, dh = w & 1;            // gate / dim-half for MFMA role
  int arow = lane & 15, s4 = lane >> 4;  // A-row (batch) / k-subgroup
  int bt = w;                            // cell role: wave = batch-in-group
  int b = g * 8 + bt;

  __shared__ __align__(16) f16 wlds[8][14][64][8];  // 112 KB: [wave][fi][lane][16B]
  __shared__ __align__(16) f16 hbuf[2][8][256];     // 8 KB, chunk-swizzled
  __shared__ __align__(16) float gq[4][8][264];     // 33 KB

  // ---- W_hh fragments ----
  v8h wr[8][6];  // kt 0..5, all ct  (192 VGPR)
  v8h wr6, wr7;  // ct 0, kt 6,7     (8 VGPR)
  {
    const f16* wp = Whh + (size_t)(q * 256 + dh * 128 + arow) * 256;
#pragma unroll
    for (int ct = 0; ct < 8; ++ct) {
      const v8h* row = (const v8h*)(wp + (size_t)ct * 16 * 256);
#pragma unroll
      for (int kt = 0; kt < 6; ++kt) wr[ct][kt] = row[kt * 4 + s4];
    }
    const v8h* row0 = (const v8h*)wp;
    wr6 = row0[6 * 4 + s4];
    wr7 = row0[7 * 4 + s4];
#pragma unroll
    for (int ct = 1; ct < 8; ++ct) {
      const v8h* row = (const v8h*)(wp + (size_t)ct * 16 * 256);
#pragma unroll
      for (int kt = 6; kt < 8; ++kt)
        *(v8h*)&wlds[w][(ct - 1) * 2 + (kt - 6)][lane][0] = row[kt * 4 + s4];
    }
  }

  // ---- init hbuf parity 0 = h_{t0-1} (zeros at t0==0), c-state ----
  if (tid < 256) {
    int row = tid >> 5, c = tid & 31;
    uint4 pk = {0u, 0u, 0u, 0u};
    if (t0 > 0) {
      const float4* hs = (const float4*)&hstate[(size_t)(g * 8 + row) * 256 + c * 8];
      float4 a = hs[0], bq = hs[1];
      pk.x = pk2(a.x, a.y);  pk.y = pk2(a.z, a.w);
      pk.z = pk2(bq.x, bq.y); pk.w = pk2(bq.z, bq.w);
    }
    *(uint4*)((char*)hbuf + hb_off(0, row, c)) = pk;
  }
  float c0 = 0.f, c1 = 0.f, c2 = 0.f, c3 = 0.f;
  if (t0 > 0) {
    float4 cc = *(const float4*)&cstate[(size_t)b * 256 + 4 * lane];
    c0 = cc.x; c1 = cc.y; c2 = cc.z; c3 = cc.w;
  }
  float h0 = 0.f, h1 = 0.f, h2 = 0.f, h3 = 0.f;

  // G pointer for cell role: [b][s][1024], this thread's 4 dims per gate
  const f16* Gb = G + (size_t)b * 262144 + 4 * lane;
  uint2 gv[4];
#pragma unroll
  for (int qg = 0; qg < 4; ++qg)
    gv[qg] = *(const uint2*)(Gb + qg * 256);  // s = 0

  __syncthreads();  // full barrier once: wlds + hbuf ready

  for (int s = 0; s < steps; ++s) {
    int p = s & 1;
    int t = t0 + s;

    // ---- MFMA phase: gates(t) = h_{t-1} x W_hh^T ----
#pragma unroll
    for (int pass = 0; pass < 2; ++pass) {
      v4f acc[4] = {{0.f, 0.f, 0.f, 0.f}, {0.f, 0.f, 0.f, 0.f},
                    {0.f, 0.f, 0.f, 0.f}, {0.f, 0.f, 0.f, 0.f}};
#pragma unroll
      for (int kt = 0; kt < 8; ++kt) {
        v8h a = *(const v8h*)((const char*)hbuf + hb_off(p, arow & 7, kt * 4 + s4));
#pragma unroll
        for (int c4 = 0; c4 < 4; ++c4) {
          const int ct = pass * 4 + c4;
          v8h bf;
          if (kt < 6) {
            bf = wr[ct][kt];
          } else if (ct == 0) {
            bf = (kt == 6) ? wr6 : wr7;
          } else {
            bf = *(const v8h*)&wlds[w][(ct - 1) * 2 + (kt - 6)][lane][0];
          }
          acc[c4] = mfma_16x16x32(a, bf, acc[c4]);
        }
      }
      // D: batch = s4*4+r (real for s4<2), dim = dh*128 + ct*16 + arow  [R7-verified]
      if (s4 < 2) {
        int r0 = s4 * 4;
#pragma unroll
        for (int c4 = 0; c4 < 4; ++c4)
#pragma unroll
          for (int r = 0; r < 4; ++r)
            gq[q][r0 + r][dh * 128 + (pass * 4 + c4) * 16 + arow] = acc[c4][r];
      }
    }
    wg_barrier();  // BAR1: gq ready (lgkm only; G prefetch stays in flight)

    // ---- cell phase: thread (bt=w, dims 4*lane..+3) ----
    {
      float4 zi = *(const float4*)&gq[0][bt][4 * lane];
      float4 zf = *(const float4*)&gq[1][bt][4 * lane];
      float4 zg = *(const float4*)&gq[2][bt][4 * lane];
      float4 zo = *(const float4*)&gq[3][bt][4 * lane];
      v2h gia = __builtin_bit_cast(v2h, gv[0].x), gib = __builtin_bit_cast(v2h, gv[0].y);
      v2h gfa = __builtin_bit_cast(v2h, gv[1].x), gfb = __builtin_bit_cast(v2h, gv[1].y);
      v2h gga = __builtin_bit_cast(v2h, gv[2].x), ggb = __builtin_bit_cast(v2h, gv[2].y);
      v2h goa = __builtin_bit_cast(v2h, gv[3].x), gob = __builtin_bit_cast(v2h, gv[3].y);

      float i0 = sigm(zi.x + (float)gia[0]), i1 = sigm(zi.y + (float)gia[1]);
      float i2 = sigm(zi.z + (float)gib[0]), i3 = sigm(zi.w + (float)gib[1]);
      float f0 = sigm(zf.x + (float)gfa[0]), f1 = sigm(zf.y + (float)gfa[1]);
      float f2 = sigm(zf.z + (float)gfb[0]), f3 = sigm(zf.w + (float)gfb[1]);
      float g0 = tanh_(zg.x + (float)gga[0]), g1 = tanh_(zg.y + (float)gga[1]);
      float g2 = tanh_(zg.z + (float)ggb[0]), g3 = tanh_(zg.w + (float)ggb[1]);
      float o0 = sigm(zo.x + (float)goa[0]), o1 = sigm(zo.y + (float)goa[1]);
      float o2 = sigm(zo.z + (float)gob[0]), o3 = sigm(zo.w + (float)gob[1]);
      c0 = f0 * c0 + i0 * g0;  c1 = f1 * c1 + i1 * g1;
      c2 = f2 * c2 + i2 * g2;  c3 = f3 * c3 + i3 * g3;
      h0 = o0 * tanh_(c0);  h1 = o1 * tanh_(c1);
      h2 = o2 * tanh_(c2);  h3 = o3 * tanh_(c3);

      // h -> hbuf[p^1] (swizzled; wave writes its own batch row: conflict-free)
      uint2 hp; hp.x = pk2(h0, h1); hp.y = pk2(h2, h3);
      *(uint2*)((char*)hbuf + hb_off(p ^ 1, bt, lane >> 1) + (lane & 1) * 8) = hp;

      // outputs (fire-and-forget)
      if (LAYER == 0) {
        if ((t & 1) == 0) {
          uint2 hr;
          hr.x = (uint32_t)__builtin_bit_cast(uint16_t, (f16)h0) |
                 ((uint32_t)__builtin_bit_cast(uint16_t, (f16)h1) << 16);
          hr.y = (uint32_t)__builtin_bit_cast(uint16_t, (f16)h2) |
                 ((uint32_t)__builtin_bit_cast(uint16_t, (f16)h3) << 16);
          *(uint2*)&Hout[((size_t)b * 512 + (t >> 1)) * 256 + 4 * lane] = hr;
        }
      } else if (LAYER == 1) {
        if ((t & 1) == 0) {
          uint2 hr;
          hr.x = (uint32_t)__builtin_bit_cast(uint16_t, (f16)h0) |
                 ((uint32_t)__builtin_bit_cast(uint16_t, (f16)h1) << 16);
          hr.y = (uint32_t)__builtin_bit_cast(uint16_t, (f16)h2) |
                 ((uint32_t)__builtin_bit_cast(uint16_t, (f16)h3) << 16);
          *(uint2*)&Hout[((size_t)b * 256 + (t >> 1)) * 256 + 4 * lane] = hr;
        }
      } else {
        size_t base = ((size_t)b * 1024 + (size_t)t * 4) * 256 + 4 * lane;
        float4 hv; hv.x = h0; hv.y = h1; hv.z = h2; hv.w = h3;
        *(float4*)&y[base] = hv;
        *(float4*)&y[base + 256] = hv;
        *(float4*)&y[base + 512] = hv;
        *(float4*)&y[base + 768] = hv;
      }

      // G prefetch for s+1 (gv free now; lands during next MFMA phase)
      if (s + 1 < steps) {
        const f16* Gs = Gb + (size_t)(s + 1) * 1024;
#pragma unroll
        for (int qg = 0; qg < 4; ++qg)
          gv[qg] = *(const uint2*)(Gs + qg * 256);
      }
    }
    wg_barrier();  // BAR2: hbuf[p^1] complete before next MFMA reads it
  }

  // ---- chunk state ----
  {
    size_t sb = (size_t)b * 256 + 4 * lane;
    float4 hv; hv.x = h0; hv.y = h1; hv.z = h2; hv.w = h3;
    float4 cv; cv.x = c0; cv.y = c1; cv.z = c2; cv.w = c3;
    *(float4*)&hstate[sb] = hv;
    *(float4*)&cstate[sb] = cv;
  }
}

// ---------------- orchestration ----------------

extern "C" void kernel_launch(void* const* d_in, const int* in_sizes, int n_in,
                              void* d_out, int out_size, void* d_ws, size_t ws_size,
                              hipStream_t stream) {
  const float* x = (const float*)d_in[0];
  const float* wih[3] = {(const float*)d_in[1], (const float*)d_in[5], (const float*)d_in[9]};
  const float* whh[3] = {(const float*)d_in[2], (const float*)d_in[6], (const float*)d_in[10]};
  const float* bi[3] = {(const float*)d_in[3], (const float*)d_in[7], (const float*)d_in[11]};
  const float* bh[3] = {(const float*)d_in[4], (const float*)d_in[8], (const float*)d_in[12]};
  float* y = (float*)d_out;

  // workspace layout (~155 MB total)
  char* p = (char*)d_ws;
  f16* Xf = (f16*)p;        p += (size_t)16777216 * 2;        // 33.5 MB
  f16* Wih0f = (f16*)p;     p += (size_t)131072 * 2;
  f16* Whh0f = (f16*)p;     p += (size_t)262144 * 2;
  f16* Wih1f = (f16*)p;     p += (size_t)262144 * 2;
  f16* Whh1f = (f16*)p;     p += (size_t)262144 * 2;
  f16* Wih2f = (f16*)p;     p += (size_t)262144 * 2;
  f16* Whh2f = (f16*)p;     p += (size_t)262144 * 2;
  float* bias0 = (float*)p; p += 4096;
  float* bias1 = (float*)p; p += 4096;
  float* bias2 = (float*)p; p += 4096;
  f16* Gbuf = (f16*)p;      p += (size_t)32768 * 1024 * 2;    // 67 MB chunk
  f16* H0e = (f16*)p;       p += (size_t)128 * 512 * 256 * 2; // 33.5 MB
  f16* H1q = (f16*)p;       p += (size_t)128 * 256 * 256 * 2; // 16.8 MB
  float* hstate = (float*)p; p += (size_t)128 * 256 * 4;
  float* cstate = (float*)p; p += (size_t)128 * 256 * 4;

  // prep
  k_cvt_x<<<4096, 256, 0, stream>>>((const float2*)x, (uint32_t*)Xf, 8388608);
  k_prep_w<<<1024, 256, 0, stream>>>(wih[0], whh[0], wih[1], whh[1], wih[2], whh[2],
                                     bi[0], bh[0], bi[1], bh[1], bi[2], bh[2],
                                     Wih0f, Whh0f, Wih1f, Whh1f, Wih2f, Whh2f,
                                     bias0, bias1, bias2);

  // layer 0: 4 chunks of 256 steps
  for (int c = 0; c < 4; ++c) {
    k_gemm<128><<<512, 256, 0, stream>>>(Xf, 1024, c * 256, Wih0f, bias0, Gbuf);
    k_rec<0><<<16, 512, 0, stream>>>(Gbuf, Whh0f, c * 256, 256, H0e, nullptr,
                                     hstate, cstate);
  }
  // layer 1: 2 chunks of 256 steps (inputs = h0 at even t)
  for (int c = 0; c < 2; ++c) {
    k_gemm<256><<<512, 256, 0, stream>>>(H0e, 512, c * 256, Wih1f, bias1, Gbuf);
    k_rec<1><<<16, 512, 0, stream>>>(Gbuf, Whh1f, c * 256, 256, H1q, nullptr,
                                     hstate, cstate);
  }
  // layer 2: 1 chunk of 256 steps (inputs = h1 at t%4==0); writes y with 4x broadcast
  k_gemm<256><<<512, 256, 0, stream>>>(H1q, 256, 0, Wih2f, bias2, Gbuf);
  k_rec<2><<<16, 512, 0, stream>>>(Gbuf, Whh2f, 0, 256, nullptr, y,
                                   hstate, cstate);
}